// Round 7
// baseline (154.563 us; speedup 1.0000x reference)
//
#include <hip/hip_runtime.h>
#include <stdint.h>

// Shapes are fixed by the reference: B=2, T=2048, C=1024, H=16, Dh=64.
#define B_   2
#define T_   2048
#define C_   1024
#define H_   16
#define BT   4096      // B_*T_
#define KDIM 1024      // inner dim of all projections

typedef unsigned short u16;
typedef __attribute__((ext_vector_type(8))) __bf16 bf16v8;   // 4 VGPR MFMA operand
typedef __attribute__((ext_vector_type(4))) float f32x4;     // 16x16 accumulator
typedef __attribute__((ext_vector_type(16))) float f32x16;   // 32x32 accumulator
typedef __attribute__((ext_vector_type(4))) unsigned int u32x4;

#define MFMA16(a, b, c) __builtin_amdgcn_mfma_f32_16x16x32_bf16((a), (b), (c), 0, 0, 0)
#define MFMA32(a, b, c) __builtin_amdgcn_mfma_f32_32x32x16_bf16((a), (b), (c), 0, 0, 0)

#define BARRIER() do { asm volatile("" ::: "memory"); \
                       __builtin_amdgcn_s_barrier();  \
                       asm volatile("" ::: "memory"); } while (0)
#define WAITVM(n) asm volatile("s_waitcnt vmcnt(" #n ")" ::: "memory")

__device__ __forceinline__ u16 f2bf(float f) {
  __bf16 h = (__bf16)f;                       // native v_cvt (RNE)
  union { __bf16 h; u16 u; } v; v.h = h;
  return v.u;
}

// async global->LDS, 16B per lane; LDS dest is wave-uniform base + lane*16
__device__ __forceinline__ void gload16(const void* g, void* l) {
  __builtin_amdgcn_global_load_lds((__attribute__((address_space(1))) void*)g,
                                   (__attribute__((address_space(3))) void*)l,
                                   16, 0, 0);
}

// ---------------------------------------------------------------- fp32->bf16
__global__ __launch_bounds__(256) void cvt_f32_bf16(const float* __restrict__ in,
                                                    u16* __restrict__ out, int n) {
  int i = (blockIdx.x * 256 + threadIdx.x) * 4;
  if (i + 3 < n) {
    float4 v = *(const float4*)(in + i);
    ushort4 o;
    o.x = f2bf(v.x); o.y = f2bf(v.y); o.z = f2bf(v.z); o.w = f2bf(v.w);
    *(ushort4*)(out + i) = o;
  }
}

// all four 1024x1024 weight matrices in one launch
__global__ __launch_bounds__(256) void cvt_weights(
    const float* __restrict__ wq, const float* __restrict__ wk,
    const float* __restrict__ wv, const float* __restrict__ wo,
    u16* __restrict__ qkv_dst, u16* __restrict__ o_dst) {
  const int bid = blockIdx.x;          // 0..4095
  const int sel = bid >> 10;
  const float* src = (sel == 0) ? wq : (sel == 1) ? wk : (sel == 2) ? wv : wo;
  u16* dst = (sel < 3) ? (qkv_dst + sel * 1048576) : o_dst;
  const int i = ((bid & 1023) * 256 + threadIdx.x) * 4;
  float4 v = *(const float4*)(src + i);
  ushort4 o;
  o.x = f2bf(v.x); o.y = f2bf(v.y); o.z = f2bf(v.z); o.w = f2bf(v.w);
  *(ushort4*)(dst + i) = o;
}

// ---------------------------------------------------------------- GEMM, 3-slot ring
// C[M=4096, N=NN] = A[M,K=1024] * Bm[NN,K]^T.  Tile BM x 128, BK=64.
// WAVES = THREADS/64 arranged (WM=WAVES/2) x 2; per-wave 64x64 output
// (4x4 16x16 frags) -> RoPE pairing (nf <-> nf+-2) stays wave-local.
// LDS: 3 slots of (BM*128B A + 16KB B) -> tile t staged into slot t%3 TWO
// groups ahead (pre-half before the group's wait, mid-half between MFMA
// phases). Steady wait vmcnt(1.5R): tile g's R loads were issued 2 groups
// (~1000cy) earlier -> latency covered, queue never drains until tail.
// Verified XOR swizzle (pre-swizzled source + swizzled ds_read, rule #21).
// EPI=0: fp32 C.  EPI=1: QKV fused RoPE+scatter (q pre-scaled 0.125*log2e).
template<int BM, int THREADS, int EPI, int NN>
__global__ __launch_bounds__(THREADS, 1) void gemm_ring(
    const u16* __restrict__ A, const u16* __restrict__ Bm,
    float* __restrict__ Cf,
    u16* __restrict__ qo, u16* __restrict__ ko, u16* __restrict__ vo,
    const float* __restrict__ cosT, const float* __restrict__ sinT)
{
  constexpr int SLOT = BM * 128 + 16384;          // A-half + B-half bytes
  constexpr int RA = 4;                           // A stage rounds (BM*8/THREADS)
  constexpr int R  = RA + (128 * 8) / THREADS;    // + B rounds: 6 (512t) / 8 (256t)
  constexpr int NBY = 4096 / BM;
  constexpr int NWG = NBY * (NN / 128);
  __shared__ __align__(16) char smem[3 * SLOT];

  const int tid = threadIdx.x;
  const int lane = tid & 63;
  const int w = tid >> 6;
  const int wm = w >> 1, wn = w & 1;
  const int lmod = lane & 15, ldiv = lane >> 4;

  // bijective XCD swizzle, by-fastest: each XCD keeps a B col-panel L2-resident
  const int swz = (blockIdx.x & 7) * (NWG >> 3) + (blockIdx.x >> 3);
  const int by = swz % NBY, bx = swz / NBY;
  const int row0 = by * BM, col0 = bx * 128;

  auto stage_part = [&](int t, int rbeg, int rend) {
    char* base = smem + (t % 3) * SLOT;
    const size_t koff = (size_t)t * 128;          // K-tile byte offset in row
#pragma unroll
    for (int r = 0; r < R; ++r) {
      if (r < rbeg || r >= rend) continue;
      if (r < RA) {
        const int row = r * (THREADS / 8) + (tid >> 3);
        const int sw  = ((tid & 7) * 16) ^ ((row & 7) << 4);
        gload16((const char*)A + (size_t)(row0 + row) * 2048 + koff + sw,
                base + r * (THREADS * 16) + tid * 16);
      } else {
        const int row = (r - RA) * (THREADS / 8) + (tid >> 3);
        const int sw  = ((tid & 7) * 16) ^ ((row & 7) << 4);
        gload16((const char*)Bm + (size_t)(col0 + row) * 2048 + koff + sw,
                base + BM * 128 + (r - RA) * (THREADS * 16) + tid * 16);
      }
    }
  };

  f32x4 acc[4][4] = {};

  stage_part(0, 0, R);                            // prologue: tiles 0 and 1
  stage_part(1, 0, R);

  for (int g = 0; g < 16; ++g) {
    const char* slot = smem + (g % 3) * SLOT;
    if (g + 2 < 16) stage_part(g + 2, 0, R / 2);  // pre-half of tile g+2
    // counted wait: tile g's R loads (issued 2 groups ago) must be done;
    // allowed outstanding = tile g+1's R + tile g+2's R/2 = 1.5R
    if (g + 2 < 16)       { if constexpr (R == 6) WAITVM(9); else WAITVM(12); }
    else if (g + 1 < 16)  { if constexpr (R == 6) WAITVM(6); else WAITVM(8); }
    else                  { WAITVM(0); }
    BARRIER();                                    // tile g visible to all waves

    bf16v8 bfr[4][2];                             // B frags held for the group
#pragma unroll
    for (int nf = 0; nf < 4; ++nf) {
      const int rr = wn * 64 + nf * 16 + lmod;
#pragma unroll
      for (int kc = 0; kc < 2; ++kc)
        bfr[nf][kc] = *(const bf16v8*)(slot + BM * 128 + rr * 128 +
                          ((kc * 64 + ldiv * 16) ^ ((rr & 7) << 4)));
    }
#pragma unroll
    for (int h = 0; h < 2; ++h) {                 // 2 phases: mf{0,1} then mf{2,3}
      bf16v8 af[2][2];
#pragma unroll
      for (int i = 0; i < 2; ++i) {
        const int rr = wm * 64 + (h * 2 + i) * 16 + lmod;
#pragma unroll
        for (int kc = 0; kc < 2; ++kc)
          af[i][kc] = *(const bf16v8*)(slot + rr * 128 +
                          ((kc * 64 + ldiv * 16) ^ ((rr & 7) << 4)));
      }
      __builtin_amdgcn_s_setprio(1);
#pragma unroll
      for (int i = 0; i < 2; ++i)
#pragma unroll
        for (int nf = 0; nf < 4; ++nf)
#pragma unroll
          for (int kc = 0; kc < 2; ++kc)
            acc[h * 2 + i][nf] = MFMA16(af[i][kc], bfr[nf][kc], acc[h * 2 + i][nf]);
      __builtin_amdgcn_s_setprio(0);
      if (h == 0 && g + 2 < 16) stage_part(g + 2, R / 2, R);   // mid-half
    }
    BARRIER();                                    // all waves done reading slot g%3
  }

  if (EPI == 0) {
#pragma unroll
    for (int mf = 0; mf < 4; ++mf) {
      const int mbase = row0 + wm * 64 + mf * 16 + ldiv * 4;
#pragma unroll
      for (int nf = 0; nf < 4; ++nf) {
        const int n = col0 + wn * 64 + nf * 16 + lmod;
#pragma unroll
        for (int r = 0; r < 4; ++r)
          Cf[(size_t)(mbase + r) * NN + n] = acc[mf][nf][r];
      }
    }
  } else {
    // wave's 64-col block is head-aligned; RoPE pair (d, d+-32) = (nf, nf+-2)
    const int nb = col0 + wn * 64;
    const int proj = nb >> 10;            // 0=q 1=k 2=v
    const int hh = (nb & 1023) >> 6;      // head
    u16* dst = (proj == 0) ? qo : (proj == 1) ? ko : vo;
#pragma unroll
    for (int mf = 0; mf < 4; ++mf) {
#pragma unroll
      for (int r = 0; r < 4; ++r) {
        const int m = row0 + wm * 64 + mf * 16 + ldiv * 4 + r;
        const int b = m >> 11, t = m & 2047;
        u16* drow = dst + ((size_t)(b * H_ + hh) * T_ + t) * 64;
#pragma unroll
        for (int nf = 0; nf < 4; ++nf) {
          const int d = nf * 16 + lmod;
          float val = acc[mf][nf][r];
          if (proj < 2) {
            const float cs = cosT[t * 64 + d];
            const float sn = sinT[t * 64 + d];
            const float other = (nf < 2) ? acc[mf][nf + 2][r] : acc[mf][nf - 2][r];
            val = (nf < 2) ? (val * cs - other * sn) : (val * cs + other * sn);
            if (proj == 0) val *= 0.18033688011112042f;  // 0.125 * log2(e)
          }
          drow[d] = f2bf(val);
        }
      }
    }
  }
}

// ---------------------------------------------------------------- V -> V^T
// v (BH, T, 64) -> vt (BH, 64, T)
__global__ __launch_bounds__(256) void transpose_v(const u16* __restrict__ v,
                                                   u16* __restrict__ vt) {
  __shared__ __align__(16) u16 tile[64][72];
  const int bh = blockIdx.x >> 5;
  const int tb = (blockIdx.x & 31) << 6;
  const int tid = threadIdx.x;
#pragma unroll
  for (int c = 0; c < 2; ++c) {
    const int idx = c * 256 + tid;
    const int r = idx >> 3, col = (idx & 7) << 3;
    *(uint4*)&tile[r][col] = *(const uint4*)&v[((size_t)bh * T_ + tb + r) * 64 + col];
  }
  __syncthreads();
#pragma unroll
  for (int c = 0; c < 2; ++c) {
    const int idx = c * 256 + tid;
    const int d = idx >> 3, col = (idx & 7) << 3;
    u16 tmp[8];
#pragma unroll
    for (int j = 0; j < 8; ++j) tmp[j] = tile[col + j][d];
    *(uint4*)&vt[((size_t)bh * 64 + d) * T_ + tb + col] = *(uint4*)tmp;
  }
}

// ---------------------------------------------------------------- O^T -> O
__global__ __launch_bounds__(256) void transpose_o(const u16* __restrict__ src,
                                                   u16* __restrict__ dst) {
  __shared__ __align__(16) u16 tile[64][72];
  const int bh = blockIdx.x >> 5;
  const int tb = (blockIdx.x & 31) << 6;
  const int tid = threadIdx.x;
#pragma unroll
  for (int c = 0; c < 2; ++c) {
    const int idx = c * 256 + tid;
    const int d = idx >> 3, col = (idx & 7) << 3;       // [d][t]
    *(uint4*)&tile[d][col] = *(const uint4*)&src[((size_t)bh * 64 + d) * T_ + tb + col];
  }
  __syncthreads();
  const int b = bh >> 4, hh = bh & 15;
#pragma unroll
  for (int c = 0; c < 2; ++c) {
    const int idx = c * 256 + tid;
    const int t = idx >> 3, col = (idx & 7) << 3;
    u16 tmp[8];
#pragma unroll
    for (int j = 0; j < 8; ++j) tmp[j] = tile[col + j][t];
    *(uint4*)&dst[((size_t)(b * T_ + tb + t)) * C_ + hh * 64 + col] = *(uint4*)tmp;
  }
}

// ---------------------------------------------------------------- attention
// Block-cooperative flash attention (unchanged from round 6).
__global__ __launch_bounds__(256, 2) void attn_fwd3(
    const u16* __restrict__ Q, const u16* __restrict__ K,
    const u16* __restrict__ Vt, u16* __restrict__ Ot)
{
  __shared__ __align__(16) u16 Kl[2][64 * 64];    // 8 KiB per buffer
  __shared__ __align__(16) u16 Vl[2][64 * 64];
  const int xcd = blockIdx.x & 7;
  const int idx = blockIdx.x >> 3;          // 0..63
  const int h   = idx & 1;
  const int j   = idx >> 1;                 // 0..31
  const int bh  = xcd * 4 + (j & 3);
  const int cr  = j >> 2;                   // 0..7
  const int chunk = h ? (15 - cr) : cr;     // q-chunk 0..15
  const int qb0 = chunk * 128;
  const int nblk = 2 * chunk + 2;           // 64-key tiles in causal range

  const int tid = threadIdx.x, lane = tid & 63, w = tid >> 6;
  const int l31 = lane & 31, hi = lane >> 5;
  const int qrow = qb0 + w * 32;

  bf16v8 qf[4];
  {
    const u16* qp = Q + ((size_t)bh * T_ + qrow + l31) * 64 + hi * 8;
    qf[0] = *(const bf16v8*)(qp);
    qf[1] = *(const bf16v8*)(qp + 16);
    qf[2] = *(const bf16v8*)(qp + 32);
    qf[3] = *(const bf16v8*)(qp + 48);
  }

  float m2 = -1e30f, lsum = 0.f;            // log2-domain running max / sum
  f32x16 oacc0 = {}, oacc1 = {};            // O^T d-blocks 0..31 / 32..63

  const int scolb = (tid & 7) * 16;         // 16B col within 128B row
  const int ldst = (tid & 192) * 16;        // wave-uniform LDS sub-base

  auto stage = [&](int buf, int t) {
    const int s0 = t << 6;
#pragma unroll
    for (int c = 0; c < 2; ++c) {
      const int row = (c * 256 + tid) >> 3;
      const int sw = scolb ^ ((row & 7) << 4);
      gload16((const char*)(K + ((size_t)bh * T_ + s0 + row) * 64) + sw,
              (char*)Kl[buf] + c * 4096 + ldst);
    }
#pragma unroll
    for (int c = 0; c < 2; ++c) {
      const int row = (c * 256 + tid) >> 3;
      const int sw = scolb ^ ((row & 7) << 4);
      gload16((const char*)(Vt + ((size_t)(bh * 64 + row)) * T_ + s0) + sw,
              (char*)Vl[buf] + c * 4096 + ldst);
    }
  };

  auto substep = [&](int cur, int sub, int s0_sub) {
    bf16v8 kf[4], vf[4];
#pragma unroll
    for (int c = 0; c < 4; ++c) {
      const int row = sub * 32 + l31;
      kf[c] = *(const bf16v8*)((const char*)Kl[cur] + row * 128 +
                  ((c * 32 + hi * 16) ^ ((row & 7) << 4)));
    }
#pragma unroll
    for (int db = 0; db < 2; ++db)
#pragma unroll
      for (int kg = 0; kg < 2; ++kg) {
        const int row = db * 32 + l31;
        vf[db * 2 + kg] = *(const bf16v8*)((const char*)Vl[cur] + row * 128 +
                  ((sub * 64 + kg * 32 + hi * 16) ^ ((row & 7) << 4)));
      }
    f32x16 s = {};
    s = MFMA32(kf[0], qf[0], s);
    s = MFMA32(kf[1], qf[1], s);
    s = MFMA32(kf[2], qf[2], s);
    s = MFMA32(kf[3], qf[3], s);
    if (s0_sub + 31 > qrow) {
#pragma unroll
      for (int r = 0; r < 16; ++r) {
        const int key = s0_sub + (r & 3) + 8 * (r >> 2) + 4 * hi;
        if (key > qrow + l31) s[r] = -1e30f;
      }
    }
    float pmax = s[0];
#pragma unroll
    for (int r = 1; r < 16; ++r) pmax = fmaxf(pmax, s[r]);
    pmax = fmaxf(pmax, __shfl_xor(pmax, 32));
    if (!__all(pmax <= m2 + 11.5416f)) {    // defer-max THR = 8*log2e
      const float mnew = fmaxf(m2, pmax);
      const float rs = __builtin_amdgcn_exp2f(m2 - mnew);
      lsum *= rs;
#pragma unroll
      for (int r = 0; r < 16; ++r) { oacc0[r] *= rs; oacc1[r] *= rs; }
      m2 = mnew;
    }
    float p[16]; float ts = 0.f;
#pragma unroll
    for (int r = 0; r < 16; ++r) {
      p[r] = __builtin_amdgcn_exp2f(s[r] - m2);
      ts += p[r];
    }
    ts += __shfl_xor(ts, 32);
    lsum += ts;
    uint32_t o[8];
#pragma unroll
    for (int jj = 0; jj < 8; ++jj) {
      const int r0 = 4 * (jj >> 1) + 2 * (jj & 1);
      uint32_t d;
      asm("v_cvt_pk_bf16_f32 %0, %1, %2" : "=v"(d) : "v"(p[r0]), "v"(p[r0 + 1]));
      o[jj] = d;
    }
    uint32_t po[8];
#pragma unroll
    for (int jj = 0; jj < 8; ++jj) po[jj] = __shfl_xor(o[jj], 32);
#pragma unroll
    for (int kg = 0; kg < 2; ++kg) {
      u32x4 fr;
      fr.x = hi ? po[4 * kg + 2] : o[4 * kg + 0];
      fr.y = hi ? po[4 * kg + 3] : o[4 * kg + 1];
      fr.z = hi ? o[4 * kg + 2] : po[4 * kg + 0];
      fr.w = hi ? o[4 * kg + 3] : po[4 * kg + 1];
      const bf16v8 pf = __builtin_bit_cast(bf16v8, fr);
      oacc0 = MFMA32(vf[kg], pf, oacc0);
      oacc1 = MFMA32(vf[2 + kg], pf, oacc1);
    }
  };

  stage(0, 0);
  for (int t = 0; t < nblk; ++t) {
    const int cur = t & 1;
    BARRIER();
    if (t + 1 < nblk) {
      stage(cur ^ 1, t + 1);
      asm volatile("s_waitcnt vmcnt(4)" ::: "memory");
    } else {
      asm volatile("s_waitcnt vmcnt(0)" ::: "memory");
    }
    BARRIER();
#pragma unroll
    for (int sub = 0; sub < 2; ++sub) {
      const int s0_sub = t * 64 + sub * 32;
      if (s0_sub <= qrow + 31) substep(cur, sub, s0_sub);
    }
  }

  const float inv = 1.f / lsum;
  u16* obase = Ot + ((size_t)bh * 64) * T_ + qrow + l31;
#pragma unroll
  for (int r = 0; r < 16; ++r) {
    const int d0 = (r & 3) + 8 * (r >> 2) + 4 * hi;
    obase[(size_t)d0 * T_]        = f2bf(oacc0[r] * inv);
    obase[(size_t)(d0 + 32) * T_] = f2bf(oacc1[r] * inv);
  }
}

// ---------------------------------------------------------------- launch
extern "C" void kernel_launch(void* const* d_in, const int* in_sizes, int n_in,
                              void* d_out, int out_size, void* d_ws, size_t ws_size,
                              hipStream_t stream) {
  const float* x    = (const float*)d_in[0];
  const float* cosT = (const float*)d_in[1];
  const float* sinT = (const float*)d_in[2];
  // d_in[3] = mask (causal by construction, unused), d_in[4] = n_heads (=16)
  const float* Wq = (const float*)d_in[5];
  const float* Wk = (const float*)d_in[6];
  const float* Wv = (const float*)d_in[7];
  const float* Wo = (const float*)d_in[8];
  float* out = (float*)d_out;

  // workspace layout (48 MB total)
  char* ws = (char*)d_ws;
  u16* xb   = (u16*)(ws);                    // bf16 x; reused as aoutT after gemm1
  u16* wqkv = (u16*)(ws + 8388608);          // [Wq;Wk;Wv] bf16
  u16* wo   = (u16*)(ws + 14680064);         // Wo bf16
  u16* q    = (u16*)(ws + 16777216);         // (B,H,T,64) bf16, roped+scaled; reused as aout
  u16* k    = (u16*)(ws + 25165824);         // (B,H,T,64) bf16, roped
  u16* v    = (u16*)(ws + 33554432);         // (B,H,T,64) bf16
  u16* vt   = (u16*)(ws + 41943040);         // (B,H,64,T) bf16
  u16* aoutT = xb;                           // attention output^T (BH,64,T)
  u16* aout  = q;                            // transposed back (B,T,C)

  cvt_f32_bf16<<<4096, 256, 0, stream>>>(x, xb, BT * C_);
  cvt_weights<<<4096, 256, 0, stream>>>(Wq, Wk, Wv, Wo, wqkv, wo);

  gemm_ring<256, 512, 1, 3072><<<384, 512, 0, stream>>>(xb, wqkv, nullptr,
                                                        q, k, v, cosT, sinT);
  transpose_v<<<1024, 256, 0, stream>>>(v, vt);
  attn_fwd3<<<512, 256, 0, stream>>>(q, k, vt, aoutT);
  transpose_o<<<1024, 256, 0, stream>>>(aoutT, aout);
  gemm_ring<128, 256, 0, 1024><<<256, 256, 0, stream>>>(aout, wo, out,
                                                        nullptr, nullptr, nullptr,
                                                        nullptr, nullptr);
}

// Round 8
// 123.710 us; speedup vs baseline: 1.2494x; 1.2494x over previous
//
#include <hip/hip_runtime.h>
#include <stdint.h>

// Shapes are fixed by the reference: B=2, T=2048, C=1024, H=16, Dh=64.
#define B_   2
#define T_   2048
#define C_   1024
#define H_   16
#define BT   4096      // B_*T_
#define KDIM 1024      // inner dim of all projections

typedef unsigned short u16;
typedef __attribute__((ext_vector_type(8))) __bf16 bf16v8;   // 4 VGPR MFMA operand
typedef __attribute__((ext_vector_type(4))) float f32x4;     // 16x16 accumulator
typedef __attribute__((ext_vector_type(16))) float f32x16;   // 32x32 accumulator
typedef __attribute__((ext_vector_type(4))) unsigned int u32x4;

#define MFMA16(a, b, c) __builtin_amdgcn_mfma_f32_16x16x32_bf16((a), (b), (c), 0, 0, 0)
#define MFMA32(a, b, c) __builtin_amdgcn_mfma_f32_32x32x16_bf16((a), (b), (c), 0, 0, 0)

#define BARRIER() do { asm volatile("" ::: "memory"); \
                       __builtin_amdgcn_s_barrier();  \
                       asm volatile("" ::: "memory"); } while (0)

__device__ __forceinline__ u16 f2bf(float f) {
  __bf16 h = (__bf16)f;                       // native v_cvt (RNE)
  union { __bf16 h; u16 u; } v; v.h = h;
  return v.u;
}

// async global->LDS, 16B per lane; LDS dest is wave-uniform base + lane*16
__device__ __forceinline__ void gload16(const void* g, void* l) {
  __builtin_amdgcn_global_load_lds((__attribute__((address_space(1))) void*)g,
                                   (__attribute__((address_space(3))) void*)l,
                                   16, 0, 0);
}

// ---------------------------------------------------------------- fp32->bf16
__global__ __launch_bounds__(256) void cvt_f32_bf16(const float* __restrict__ in,
                                                    u16* __restrict__ out, int n) {
  int i = (blockIdx.x * 256 + threadIdx.x) * 4;
  if (i + 3 < n) {
    float4 v = *(const float4*)(in + i);
    ushort4 o;
    o.x = f2bf(v.x); o.y = f2bf(v.y); o.z = f2bf(v.z); o.w = f2bf(v.w);
    *(ushort4*)(out + i) = o;
  }
}

// all four 1024x1024 weight matrices in one launch
__global__ __launch_bounds__(256) void cvt_weights(
    const float* __restrict__ wq, const float* __restrict__ wk,
    const float* __restrict__ wv, const float* __restrict__ wo,
    u16* __restrict__ qkv_dst, u16* __restrict__ o_dst) {
  const int bid = blockIdx.x;          // 0..4095
  const int sel = bid >> 10;
  const float* src = (sel == 0) ? wq : (sel == 1) ? wk : (sel == 2) ? wv : wo;
  u16* dst = (sel < 3) ? (qkv_dst + sel * 1048576) : o_dst;
  const int i = ((bid & 1023) * 256 + threadIdx.x) * 4;
  float4 v = *(const float4*)(src + i);
  ushort4 o;
  o.x = f2bf(v.x); o.y = f2bf(v.y); o.z = f2bf(v.z); o.w = f2bf(v.w);
  *(ushort4*)(dst + i) = o;
}

// ---------------------------------------------------------------- GEMM 128x128
// C[M=4096, N=NN] = A[M,K=1024] * Bm[NN,K]^T.  BK=64, 4 waves (2x2), each wave
// a 64x64 quadrant (4x4 frags). 64 KiB double-buffered swizzled LDS -> 2
// blocks/CU; counted vmcnt(8). LOCALITY swizzle: each XCD owns a compact
// by x bx sub-grid (QKV: 8x12 -> A 2MB + B 3MB; Wo: 4x8 -> 3MB), by-fastest
// order so the ~resident set stays L2-sized -> staging hits L2, not L3.
// EPI=0: fp32 C.  EPI=1: QKV fused: q/k RoPE+scatter (q pre-scaled
// 0.125*log2e); V blocks write V^T directly via post-loop LDS bounce.
template<int EPI, int NN>
__global__ __launch_bounds__(256, 2) void gemm128(
    const u16* __restrict__ A, const u16* __restrict__ Bm,
    float* __restrict__ Cf,
    u16* __restrict__ qo, u16* __restrict__ ko, u16* __restrict__ vt,
    const float* __restrict__ cosT, const float* __restrict__ sinT)
{
  __shared__ __align__(16) u16 As[2][128 * 64];   // 32 KiB
  __shared__ __align__(16) u16 Bs[2][128 * 64];   // 32 KiB
  const int tid = threadIdx.x;
  const int lane = tid & 63;
  const int w = tid >> 6;
  const int wm = w >> 1, wn = w & 1;
  const int lmod = lane & 15, ldiv = lane >> 4;

  // locality-first XCD swizzle
  constexpr int NBX = NN / 128;                   // 24 or 8
  constexpr int XG_BY = (NBX == 24) ? 8 : 4;      // by rows per XCD group
  constexpr int XG_BX = (NBX == 24) ? 12 : 8;     // bx cols per XCD group
  const int x = blockIdx.x & 7;
  const int i = blockIdx.x >> 3;
  const int gy = (NBX == 24) ? (x >> 1) : x;
  const int gx = (NBX == 24) ? (x & 1) : 0;
  const int by = gy * XG_BY + (i % XG_BY);
  const int bx = gx * XG_BX + (i / XG_BY);
  const int row0 = by * 128, col0 = bx * 128;

  const int srow = tid >> 3;                      // 0..31
  const int sswz = ((tid & 7) * 16) ^ ((srow & 7) << 4);
  const char* Abase = (const char*)A + (size_t)(row0 + srow) * (KDIM * 2) + sswz;
  const char* Bbase = (const char*)Bm + (size_t)(col0 + srow) * (KDIM * 2) + sswz;
  const int ldst = (tid & 192) * 16;              // wave-uniform LDS sub-base

  auto stage = [&](int buf, int t) {
    const int kb = t * 128;                       // K-tile byte offset in row
#pragma unroll
    for (int c = 0; c < 4; ++c)
      gload16(Abase + (size_t)c * 32 * (KDIM * 2) + kb,
              (char*)As[buf] + c * 4096 + ldst);
#pragma unroll
    for (int c = 0; c < 4; ++c)
      gload16(Bbase + (size_t)c * 32 * (KDIM * 2) + kb,
              (char*)Bs[buf] + c * 4096 + ldst);
  };

  f32x4 acc[4][4] = {};
  stage(0, 0);

  for (int t = 0; t < KDIM / 64; ++t) {
    const int cur = t & 1;
    BARRIER();                                    // all waves done reading buf[cur^1]
    if (t + 1 < KDIM / 64) {
      stage(cur ^ 1, t + 1);                      // 8 loads for t+1 in flight
      asm volatile("s_waitcnt vmcnt(8)" ::: "memory");   // tile t landed
    } else {
      asm volatile("s_waitcnt vmcnt(0)" ::: "memory");
    }
    BARRIER();                                    // cross-wave: tile t visible

    bf16v8 af[4][2], bfr[4][2];
#pragma unroll
    for (int mf = 0; mf < 4; ++mf) {
      const int rr = wm * 64 + mf * 16 + lmod;
#pragma unroll
      for (int kc = 0; kc < 2; ++kc)
        af[mf][kc] = *(const bf16v8*)((const char*)As[cur] + rr * 128 +
                          ((kc * 64 + ldiv * 16) ^ ((rr & 7) << 4)));
    }
#pragma unroll
    for (int nf = 0; nf < 4; ++nf) {
      const int rr = wn * 64 + nf * 16 + lmod;
#pragma unroll
      for (int kc = 0; kc < 2; ++kc)
        bfr[nf][kc] = *(const bf16v8*)((const char*)Bs[cur] + rr * 128 +
                          ((kc * 64 + ldiv * 16) ^ ((rr & 7) << 4)));
    }
#pragma unroll
    for (int kc = 0; kc < 2; ++kc)
#pragma unroll
      for (int mf = 0; mf < 4; ++mf)
#pragma unroll
        for (int nf = 0; nf < 4; ++nf)
          acc[mf][nf] = MFMA16(af[mf][kc], bfr[nf][kc], acc[mf][nf]);
  }

  if (EPI == 0) {
#pragma unroll
    for (int mf = 0; mf < 4; ++mf) {
      const int mbase = row0 + wm * 64 + mf * 16 + ldiv * 4;
#pragma unroll
      for (int nf = 0; nf < 4; ++nf) {
        const int n = col0 + wn * 64 + nf * 16 + lmod;
#pragma unroll
        for (int r = 0; r < 4; ++r)
          Cf[(size_t)(mbase + r) * NN + n] = acc[mf][nf][r];
      }
    }
  } else {
    const int nb = col0 + wn * 64;
    const int proj = nb >> 10;            // 0=q 1=k 2=v  (block-uniform: col0%1024 <= 896)
    const int hh = (nb & 1023) >> 6;      // head
    if (proj < 2) {
      u16* dst = proj ? ko : qo;
#pragma unroll
      for (int mf = 0; mf < 4; ++mf) {
#pragma unroll
        for (int r = 0; r < 4; ++r) {
          const int m = row0 + wm * 64 + mf * 16 + ldiv * 4 + r;
          const int b = m >> 11, t = m & 2047;
          u16* drow = dst + ((size_t)(b * H_ + hh) * T_ + t) * 64;
#pragma unroll
          for (int nf = 0; nf < 4; ++nf) {
            const int d = nf * 16 + lmod;
            const float cs = cosT[t * 64 + d];
            const float sn = sinT[t * 64 + d];
            const float other = (nf < 2) ? acc[mf][nf + 2][r] : acc[mf][nf - 2][r];
            float val = (nf < 2) ? (acc[mf][nf][r] * cs - other * sn)
                                 : (acc[mf][nf][r] * cs + other * sn);
            if (proj == 0) val *= 0.18033688011112042f;  // 0.125 * log2(e)
            drow[d] = f2bf(val);
          }
        }
      }
    } else {
      // V^T direct: LDS bounce [d][t] (XOR-swizzled), then coalesced 128B rows
      BARRIER();                                   // everyone done with As/Bs
      char* scr = (char*)As + w * 8192;            // 8 KB per wave
#pragma unroll
      for (int nf = 0; nf < 4; ++nf)
#pragma unroll
        for (int mf = 0; mf < 4; ++mf)
#pragma unroll
          for (int rp = 0; rp < 2; ++rp) {
            const int dd = nf * 16 + lmod;
            const int t0 = mf * 16 + ldiv * 4 + rp * 2;
            const uint32_t pk = (uint32_t)f2bf(acc[mf][nf][rp * 2]) |
                                ((uint32_t)f2bf(acc[mf][nf][rp * 2 + 1]) << 16);
            *(uint32_t*)(scr + ((dd * 128 + t0 * 2) ^ ((dd & 7) << 4))) = pk;
          }
      __syncthreads();
      const int trow = row0 + wm * 64;             // this wave's 64 t-values
      const int bb = trow >> 11, tl = trow & 2047;
#pragma unroll
      for (int j = 0; j < 8; ++j) {
        const int dd = j * 8 + (lane >> 3);
        const int c = lane & 7;
        const u32x4 vv = *(const u32x4*)(scr + ((dd * 128 + c * 16) ^ ((dd & 7) << 4)));
        u16* drow = vt + ((size_t)((bb * H_ + hh) * 64 + dd)) * T_ + tl;
        *(u32x4*)((char*)drow + c * 16) = vv;
      }
    }
  }
}

// ---------------------------------------------------------------- attention
// Block-cooperative flash attention (round-6 structure). Epilogue now writes
// O directly in (B,T,C) via an LDS bounce (Kl is free post-loop) -> the
// transpose_o kernel is gone.
__global__ __launch_bounds__(256, 2) void attn_fwd3(
    const u16* __restrict__ Q, const u16* __restrict__ K,
    const u16* __restrict__ Vt, u16* __restrict__ O)
{
  __shared__ __align__(16) u16 Kl[2][64 * 64];    // 8 KiB per buffer
  __shared__ __align__(16) u16 Vl[2][64 * 64];
  const int xcd = blockIdx.x & 7;
  const int idx = blockIdx.x >> 3;          // 0..63
  const int h   = idx & 1;
  const int j   = idx >> 1;                 // 0..31
  const int bh  = xcd * 4 + (j & 3);
  const int cr  = j >> 2;                   // 0..7
  const int chunk = h ? (15 - cr) : cr;     // q-chunk 0..15
  const int qb0 = chunk * 128;
  const int nblk = 2 * chunk + 2;           // 64-key tiles in causal range

  const int tid = threadIdx.x, lane = tid & 63, w = tid >> 6;
  const int l31 = lane & 31, hi = lane >> 5;
  const int qrow = qb0 + w * 32;

  bf16v8 qf[4];
  {
    const u16* qp = Q + ((size_t)bh * T_ + qrow + l31) * 64 + hi * 8;
    qf[0] = *(const bf16v8*)(qp);
    qf[1] = *(const bf16v8*)(qp + 16);
    qf[2] = *(const bf16v8*)(qp + 32);
    qf[3] = *(const bf16v8*)(qp + 48);
  }

  float m2 = -1e30f, lsum = 0.f;            // log2-domain running max / sum
  f32x16 oacc0 = {}, oacc1 = {};            // O^T d-blocks 0..31 / 32..63

  const int scolb = (tid & 7) * 16;         // 16B col within 128B row
  const int ldst = (tid & 192) * 16;        // wave-uniform LDS sub-base

  auto stage = [&](int buf, int t) {
    const int s0 = t << 6;
#pragma unroll
    for (int c = 0; c < 2; ++c) {
      const int row = (c * 256 + tid) >> 3;
      const int sw = scolb ^ ((row & 7) << 4);
      gload16((const char*)(K + ((size_t)bh * T_ + s0 + row) * 64) + sw,
              (char*)Kl[buf] + c * 4096 + ldst);
    }
#pragma unroll
    for (int c = 0; c < 2; ++c) {
      const int row = (c * 256 + tid) >> 3;
      const int sw = scolb ^ ((row & 7) << 4);
      gload16((const char*)(Vt + ((size_t)(bh * 64 + row)) * T_ + s0) + sw,
              (char*)Vl[buf] + c * 4096 + ldst);
    }
  };

  auto substep = [&](int cur, int sub, int s0_sub) {
    bf16v8 kf[4], vf[4];
#pragma unroll
    for (int c = 0; c < 4; ++c) {
      const int row = sub * 32 + l31;
      kf[c] = *(const bf16v8*)((const char*)Kl[cur] + row * 128 +
                  ((c * 32 + hi * 16) ^ ((row & 7) << 4)));
    }
#pragma unroll
    for (int db = 0; db < 2; ++db)
#pragma unroll
      for (int kg = 0; kg < 2; ++kg) {
        const int row = db * 32 + l31;
        vf[db * 2 + kg] = *(const bf16v8*)((const char*)Vl[cur] + row * 128 +
                  ((sub * 64 + kg * 32 + hi * 16) ^ ((row & 7) << 4)));
      }
    f32x16 s = {};
    s = MFMA32(kf[0], qf[0], s);
    s = MFMA32(kf[1], qf[1], s);
    s = MFMA32(kf[2], qf[2], s);
    s = MFMA32(kf[3], qf[3], s);
    if (s0_sub + 31 > qrow) {
#pragma unroll
      for (int r = 0; r < 16; ++r) {
        const int key = s0_sub + (r & 3) + 8 * (r >> 2) + 4 * hi;
        if (key > qrow + l31) s[r] = -1e30f;
      }
    }
    float pmax = s[0];
#pragma unroll
    for (int r = 1; r < 16; ++r) pmax = fmaxf(pmax, s[r]);
    pmax = fmaxf(pmax, __shfl_xor(pmax, 32));
    if (!__all(pmax <= m2 + 11.5416f)) {    // defer-max THR = 8*log2e
      const float mnew = fmaxf(m2, pmax);
      const float rs = __builtin_amdgcn_exp2f(m2 - mnew);
      lsum *= rs;
#pragma unroll
      for (int r = 0; r < 16; ++r) { oacc0[r] *= rs; oacc1[r] *= rs; }
      m2 = mnew;
    }
    float p[16]; float ts = 0.f;
#pragma unroll
    for (int r = 0; r < 16; ++r) {
      p[r] = __builtin_amdgcn_exp2f(s[r] - m2);
      ts += p[r];
    }
    ts += __shfl_xor(ts, 32);
    lsum += ts;
    uint32_t o[8];
#pragma unroll
    for (int jj = 0; jj < 8; ++jj) {
      const int r0 = 4 * (jj >> 1) + 2 * (jj & 1);
      uint32_t d;
      asm("v_cvt_pk_bf16_f32 %0, %1, %2" : "=v"(d) : "v"(p[r0]), "v"(p[r0 + 1]));
      o[jj] = d;
    }
    uint32_t po[8];
#pragma unroll
    for (int jj = 0; jj < 8; ++jj) po[jj] = __shfl_xor(o[jj], 32);
#pragma unroll
    for (int kg = 0; kg < 2; ++kg) {
      u32x4 fr;
      fr.x = hi ? po[4 * kg + 2] : o[4 * kg + 0];
      fr.y = hi ? po[4 * kg + 3] : o[4 * kg + 1];
      fr.z = hi ? o[4 * kg + 2] : po[4 * kg + 0];
      fr.w = hi ? o[4 * kg + 3] : po[4 * kg + 1];
      const bf16v8 pf = __builtin_bit_cast(bf16v8, fr);
      oacc0 = MFMA32(vf[kg], pf, oacc0);
      oacc1 = MFMA32(vf[2 + kg], pf, oacc1);
    }
  };

  stage(0, 0);
  for (int t = 0; t < nblk; ++t) {
    const int cur = t & 1;
    BARRIER();
    if (t + 1 < nblk) {
      stage(cur ^ 1, t + 1);
      asm volatile("s_waitcnt vmcnt(4)" ::: "memory");
    } else {
      asm volatile("s_waitcnt vmcnt(0)" ::: "memory");
    }
    BARRIER();
#pragma unroll
    for (int sub = 0; sub < 2; ++sub) {
      const int s0_sub = t * 64 + sub * 32;
      if (s0_sub <= qrow + 31) substep(cur, sub, s0_sub);
    }
  }

  // epilogue: O^T frags -> LDS bounce (swizzled) -> coalesced (B,T,C) rows
  BARRIER();                                // all waves done with Kl/Vl
  char* scr = (char*)Kl + w * 4096;         // 4 KB per wave: [q=32][d=64] bf16
  const float inv = 1.f / lsum;
#pragma unroll
  for (int r2 = 0; r2 < 8; ++r2) {
    const int r = r2 * 2;                   // regs r, r+1 are adjacent d
    const int dd = (r & 3) + 8 * (r >> 2) + 4 * hi;
    const uint32_t pk0 = (uint32_t)f2bf(oacc0[r] * inv) |
                         ((uint32_t)f2bf(oacc0[r + 1] * inv) << 16);
    *(uint32_t*)(scr + ((l31 * 128 + dd * 2) ^ ((l31 & 7) << 4))) = pk0;
    const uint32_t pk1 = (uint32_t)f2bf(oacc1[r] * inv) |
                         ((uint32_t)f2bf(oacc1[r + 1] * inv) << 16);
    *(uint32_t*)(scr + ((l31 * 128 + (dd + 32) * 2) ^ ((l31 & 7) << 4))) = pk1;
  }
  __syncthreads();
  const int b = bh >> 4, hh = bh & 15;
  const int qq = lane >> 1, cc = lane & 1;  // 2 lanes per output row
  u16* orow = O + ((size_t)(b * T_ + qrow + qq)) * C_ + hh * 64 + cc * 32;
#pragma unroll
  for (int jj = 0; jj < 4; ++jj) {
    const u32x4 vv = *(const u32x4*)(scr + ((qq * 128 + cc * 64 + jj * 16) ^ ((qq & 7) << 4)));
    *(u32x4*)((char*)orow + jj * 16) = vv;
  }
}

// ---------------------------------------------------------------- launch
extern "C" void kernel_launch(void* const* d_in, const int* in_sizes, int n_in,
                              void* d_out, int out_size, void* d_ws, size_t ws_size,
                              hipStream_t stream) {
  const float* x    = (const float*)d_in[0];
  const float* cosT = (const float*)d_in[1];
  const float* sinT = (const float*)d_in[2];
  // d_in[3] = mask (causal by construction, unused), d_in[4] = n_heads (=16)
  const float* Wq = (const float*)d_in[5];
  const float* Wk = (const float*)d_in[6];
  const float* Wv = (const float*)d_in[7];
  const float* Wo = (const float*)d_in[8];
  float* out = (float*)d_out;

  // workspace layout (48 MB total)
  char* ws = (char*)d_ws;
  u16* xb   = (u16*)(ws);                    // bf16 x
  u16* wqkv = (u16*)(ws + 8388608);          // [Wq;Wk;Wv] bf16
  u16* wo   = (u16*)(ws + 14680064);         // Wo bf16
  u16* q    = (u16*)(ws + 16777216);         // (B,H,T,64) bf16, roped+scaled
  u16* k    = (u16*)(ws + 25165824);         // (B,H,T,64) bf16, roped
  u16* vt   = (u16*)(ws + 33554432);         // (B,H,64,T) bf16 (direct from gemm)
  u16* aout = (u16*)(ws + 41943040);         // attention output (B,T,C) bf16

  cvt_f32_bf16<<<4096, 256, 0, stream>>>(x, xb, BT * C_);
  cvt_weights<<<4096, 256, 0, stream>>>(Wq, Wk, Wv, Wo, wqkv, wo);

  gemm128<1, 3072><<<768, 256, 0, stream>>>(xb, wqkv, nullptr,
                                            q, k, vt, cosT, sinT);
  attn_fwd3<<<512, 256, 0, stream>>>(q, k, vt, aout);
  gemm128<0, 1024><<<256, 256, 0, stream>>>(aout, wo, out,
                                            nullptr, nullptr, nullptr,
                                            nullptr, nullptr);
}